// Round 9
// baseline (182.856 us; speedup 1.0000x reference)
//
#include <hip/hip_runtime.h>

// ---------- problem constants ----------
#define BATCH   2
#define SEQ     2048
#define DMODEL  1024
#define NHEAD   16
#define DKH     64
#define MTOT    (BATCH*SEQ)      // 4096 rows for the projection GEMMs
#define KDIM    DMODEL           // 1024 contraction for projections

// ws layout in bf16 elements (total 24M bf16 = 48 MB)
#define XB    0u                     // x bf16            [4096,1024]  4M
#define WQB   (4u*1024u*1024u)       // Wq bf16           [1024,1024]  1M
#define WKB   (5u*1024u*1024u)
#define WVB   (6u*1024u*1024u)
#define WOB   (7u*1024u*1024u)
#define QOFF  (8u*1024u*1024u)       // Q  [B,H,N,dk] (pre-scaled log2e/8) 4M
#define KOFF  (12u*1024u*1024u)      // K  [B,H,N,dk]                  4M
#define VOFF  (16u*1024u*1024u)      // V^T [B,H,dk,N]                 4M
#define OOFF  (20u*1024u*1024u)      // attn out, flat [B,N,D]         4M

typedef __bf16 bf16x8 __attribute__((ext_vector_type(8)));
typedef __bf16 bf16x4 __attribute__((ext_vector_type(4)));
typedef float  f32x4  __attribute__((ext_vector_type(4)));
typedef float  f32x16 __attribute__((ext_vector_type(16)));

// async global->LDS, 16B per lane; LDS dest is wave-uniform base (HW adds lane*16)
__device__ __forceinline__ void async16(const __bf16* g, __bf16* l) {
  __builtin_amdgcn_global_load_lds(
      (const __attribute__((address_space(1))) void*)g,
      (__attribute__((address_space(3))) void*)l, 16, 0, 0);
}

// counted waits (T4): compiler-level memory fence + hw wait, NO full drain.
// vmcnt is FIFO: waiting to <=N outstanding retires the oldest first.
#define VWAIT(N) asm volatile("s_waitcnt vmcnt(" #N ")" ::: "memory")

// packed f32x2 -> bf16x2 (dword): lo in low 16 bits (T12 recipe, no builtin)
__device__ __forceinline__ unsigned cvtpk_bf16(float lo, float hi) {
  unsigned r;
  asm("v_cvt_pk_bf16_f32 %0, %1, %2" : "=v"(r) : "v"(lo), "v"(hi));
  return r;
}
// v_permlane32_swap_b32: a.hi32lanes <-> b.lo32lanes
__device__ __forceinline__ void plswap(unsigned& a, unsigned& b) {
  asm("v_permlane32_swap_b32 %0, %1" : "+v"(a), "+v"(b));
}

// ---------------------------------------------------------------------------
// fp32 -> bf16 conversion: blockIdx.y selects tensor (0:x, 1..4:Wq/Wk/Wv/Wo)
// ---------------------------------------------------------------------------
__global__ __launch_bounds__(256) void cvt_fp32_bf16(
    const float* __restrict__ x,  const float* __restrict__ wq,
    const float* __restrict__ wk, const float* __restrict__ wv,
    const float* __restrict__ wo, __bf16* __restrict__ ws)
{
  const float* src; __bf16* dst; int n;
  switch (blockIdx.y) {
    case 0:  src = x;  dst = ws + XB;  n = 4 * 1024 * 1024; break;
    case 1:  src = wq; dst = ws + WQB; n = 1024 * 1024;     break;
    case 2:  src = wk; dst = ws + WKB; n = 1024 * 1024;     break;
    case 3:  src = wv; dst = ws + WVB; n = 1024 * 1024;     break;
    default: src = wo; dst = ws + WOB; n = 1024 * 1024;     break;
  }
  const int i = (blockIdx.x * 256 + threadIdx.x) * 8;
  if (i < n) {
    const float4 a = *(const float4*)(src + i);
    const float4 b = *(const float4*)(src + i + 4);
    bf16x8 o;
    o[0] = (__bf16)a.x; o[1] = (__bf16)a.y; o[2] = (__bf16)a.z; o[3] = (__bf16)a.w;
    o[4] = (__bf16)b.x; o[5] = (__bf16)b.y; o[6] = (__bf16)b.z; o[7] = (__bf16)b.w;
    *(bf16x8*)(dst + i) = o;
  }
}

// ---------------------------------------------------------------------------
// 128x128 NT-GEMM core — R8 (verified +): TRIPLE-BUFFERED K-loop, counted
// vmcnt + raw s_barrier (T4). LDS: 3 slots x (A 4096 | B 4096) = 48 KB.
// ---------------------------------------------------------------------------
__device__ __forceinline__ void gemm_stage128(
    const __bf16* __restrict__ A, const __bf16* __restrict__ W,
    int m0, int n0, int kt, __bf16* slot, int w, int lane)
{
#pragma unroll
  for (int issue = 0; issue < 2; ++issue) {
    const int cbase = issue * 256 + (w << 6);
    const int c     = cbase + lane;
    const int row   = c >> 2;                       // 4 chunks (32 bf16) per row
    const int goff  = ((c & 3) ^ (row & 3)) << 3;   // swizzled source chunk
    async16(A + (size_t)(m0 + row) * KDIM + kt + goff, slot + cbase * 8);
    async16(W + (size_t)(n0 + row) * KDIM + kt + goff, slot + 4096 + cbase * 8);
  }
}

__device__ __forceinline__ void gemm_step128(
    const __bf16* slot, int wr, int wc, int ln15, int quad, f32x4 (&acc)[4][4])
{
  const __bf16* A_lds = slot;
  const __bf16* B_lds = slot + 4096;
  bf16x8 af[4], bfr[4];
#pragma unroll
  for (int i = 0; i < 4; ++i) {
    const int row = wr + i * 16 + ln15;
    af[i] = *(const bf16x8*)&A_lds[row * 32 + ((quad ^ (row & 3)) << 3)];
  }
#pragma unroll
  for (int j = 0; j < 4; ++j) {
    const int row = wc + j * 16 + ln15;
    bfr[j] = *(const bf16x8*)&B_lds[row * 32 + ((quad ^ (row & 3)) << 3)];
  }
#pragma unroll
  for (int i = 0; i < 4; ++i)
#pragma unroll
    for (int j = 0; j < 4; ++j)
      acc[i][j] = __builtin_amdgcn_mfma_f32_16x16x32_bf16(af[i], bfr[j], acc[i][j], 0, 0, 0);
}

__device__ __forceinline__ void gemm128_core(
    const __bf16* __restrict__ A, const __bf16* __restrict__ W,
    int m0, int n0, __bf16* lds, f32x4 (&acc)[4][4])
{
  const int t    = threadIdx.x;
  const int w    = t >> 6;
  const int lane = t & 63;
  const int ln15 = lane & 15;
  const int quad = lane >> 4;
  const int wr   = (w >> 1) << 6;   // wave row offset within 128
  const int wc   = (w & 1) << 6;    // wave col offset within 128

#pragma unroll
  for (int i = 0; i < 4; ++i)
#pragma unroll
    for (int j = 0; j < 4; ++j) acc[i][j] = (f32x4){0.f, 0.f, 0.f, 0.f};

  __bf16* s0 = lds;             // slot of tile i   (i%3==0)
  __bf16* s1 = lds + 8192;      // slot of tile i+1
  __bf16* s2 = lds + 16384;     // slot of tile i+2

  // prologue: tiles 0,1 in flight (8 outstanding loads/thread)
  gemm_stage128(A, W, m0, n0, 0,  s0, w, lane);
  gemm_stage128(A, W, m0, n0, 32, s1, w, lane);

  // main loop: tiles 0..29, 3-unrolled for static slot rotation
  int kt = 0;
#pragma unroll 1
  for (int i3 = 0; i3 < 10; ++i3) {
    VWAIT(4); __builtin_amdgcn_s_barrier();
    gemm_stage128(A, W, m0, n0, kt + 64, s2, w, lane);
    gemm_step128(s0, wr, wc, ln15, quad, acc);

    VWAIT(4); __builtin_amdgcn_s_barrier();
    gemm_stage128(A, W, m0, n0, kt + 96, s0, w, lane);
    gemm_step128(s1, wr, wc, ln15, quad, acc);

    VWAIT(4); __builtin_amdgcn_s_barrier();
    gemm_stage128(A, W, m0, n0, kt + 128, s1, w, lane);
    gemm_step128(s2, wr, wc, ln15, quad, acc);
    kt += 96;
  }
  // peeled tail: tile 30 (slot0, tile 31 still flying), then tile 31 (drain)
  VWAIT(4); __builtin_amdgcn_s_barrier();
  gemm_step128(s0, wr, wc, ln15, quad, acc);
  VWAIT(0); __builtin_amdgcn_s_barrier();
  gemm_step128(s1, wr, wc, ln15, quad, acc);
}

// ---------------------------------------------------------------------------
// Fused QKV projection: z=0 -> Q (scaled log2e/8) [B,H,N,dk]; z=1 -> K;
// z=2 -> V transposed [B,H,dk,N]. Biases fp32. 16B vectorized stores via
// per-wave LDS repack.
// ---------------------------------------------------------------------------
__global__ __launch_bounds__(256) void qkv_gemm(
    const __bf16* __restrict__ X,
    const __bf16* __restrict__ Wq, const float* __restrict__ bq,
    const __bf16* __restrict__ Wk, const float* __restrict__ bk,
    const __bf16* __restrict__ Wv, const float* __restrict__ bv,
    __bf16* __restrict__ ws)
{
  __shared__ __align__(16) __bf16 lds[24576];   // 48 KB: 3 K-slots

  const int z = blockIdx.z;
  const __bf16* W    = (z == 0) ? Wq : (z == 1) ? Wk : Wv;
  const float*  bias = (z == 0) ? bq : (z == 1) ? bk : bv;
  __bf16* out = ws + ((z == 0) ? QOFF : (z == 1) ? KOFF : VOFF);
  // softmax runs in exp2 domain: fold 1/sqrt(dk) * log2(e) into Q
  const float scale = (z == 0) ? 0.125f * 1.44269504088896f : 1.0f;

  const int m0 = blockIdx.x * 128;
  const int n0 = blockIdx.y * 128;

  f32x4 acc[4][4];
  gemm128_core(X, W, m0, n0, lds, acc);

  const int t = threadIdx.x, w = t >> 6, lane = t & 63;
  const int ln15 = lane & 15, quad = lane >> 4;
  const int wr = (w >> 1) << 6, wc = (w & 1) << 6;

  // bias values for this wave's 64 columns (col = j*16+ln15)
  float bj4[4];
#pragma unroll
  for (int j = 0; j < 4; ++j) bj4[j] = bias[n0 + wc + j * 16 + ln15];

  __syncthreads();                     // all waves done reading K-tiles
  __bf16* scr = lds + (w << 10);       // per-wave 1024-elem scratch (2 KB)

  const int bb = m0 >> 11;             // batch (blocks never straddle)
  const int s_base = (m0 & 2047) + wr;
  const int h = (n0 + wc) >> 6;

  if (z != 2) {
    // ---- Q/K [B,H,N,dk]: row-major scratch [row16][d64], coalesced stores
    const int rdrow = lane & 15, rdseg = lane >> 4;
#pragma unroll
    for (int i = 0; i < 4; ++i) {
#pragma unroll
      for (int j = 0; j < 4; ++j)
#pragma unroll
        for (int rr = 0; rr < 4; ++rr)
          scr[(quad * 4 + rr) * 64 + j * 16 + ln15] =
              (__bf16)((acc[i][j][rr] + bj4[j]) * scale);
      // wave-private scratch: compiler orders via lgkmcnt, no barrier
      bf16x8 v0 = *(const bf16x8*)&scr[rdrow * 64 + rdseg * 16];
      bf16x8 v1 = *(const bf16x8*)&scr[rdrow * 64 + rdseg * 16 + 8];
      const int s = s_base + i * 16 + rdrow;
      __bf16* p = out + (((size_t)(bb * NHEAD + h)) * SEQ + s) * DKH + rdseg * 16;
      *(bf16x8*)p = v0;
      *(bf16x8*)&p[8] = v1;
    }
  } else {
    // ---- V^T [B,H,dk,N]: col-major scratch [d64][row16] does the transpose;
    // each lane then stores 32B contiguous in s.
#pragma unroll
    for (int i = 0; i < 4; ++i) {
#pragma unroll
      for (int j = 0; j < 4; ++j) {
        bf16x4 pk;
#pragma unroll
        for (int rr = 0; rr < 4; ++rr) pk[rr] = (__bf16)(acc[i][j][rr] + bj4[j]);
        *(bf16x4*)&scr[(j * 16 + ln15) * 16 + quad * 4] = pk;
      }
      bf16x8 c0 = *(const bf16x8*)&scr[lane * 16];
      bf16x8 c1 = *(const bf16x8*)&scr[lane * 16 + 8];
      __bf16* p = out + (((size_t)(bb * NHEAD + h)) * DKH + lane) * SEQ
                      + s_base + i * 16;
      *(bf16x8*)p = c0;
      *(bf16x8*)&p[8] = c1;
    }
  }
}

// ---------------------------------------------------------------------------
// Output projection: d_out(fp32) = O[M,K]bf16 @ Wo[N,K]bf16^T + bo(fp32).
// 64x128 tile -> 512 blocks (2/CU). T4 triple-buffer K-loop (R8, verified).
// LDS: 3 x 6144 = 36 KB.
// ---------------------------------------------------------------------------
__device__ __forceinline__ void out_stage(
    const __bf16* __restrict__ A, const __bf16* __restrict__ Wo,
    int m0, int n0, int kt, __bf16* slot, int w, int lane)
{
  {  // A: 64 rows x 4 chunks = 256 chunks = 1 issue
    const int c = (w << 6) + lane;
    const int row = c >> 2;
    const int goff = ((c & 3) ^ (row & 3)) << 3;
    async16(A + (size_t)(m0 + row) * KDIM + kt + goff, slot + c * 8);
  }
#pragma unroll
  for (int issue = 0; issue < 2; ++issue) {  // B: 128 rows x 4 chunks = 2 issues
    const int cbase = issue * 256 + (w << 6);
    const int c = cbase + lane;
    const int row = c >> 2;
    const int goff = ((c & 3) ^ (row & 3)) << 3;
    async16(Wo + (size_t)(n0 + row) * KDIM + kt + goff, slot + 2048 + cbase * 8);
  }
}

__device__ __forceinline__ void out_step(
    const __bf16* slot, int w, int ln15, int quad, f32x4 (&acc)[4][2])
{
  const __bf16* A_lds = slot;
  const __bf16* B_lds = slot + 2048;
  bf16x8 af[4], bfr[2];
#pragma unroll
  for (int i = 0; i < 4; ++i) {
    const int row = i * 16 + ln15;
    af[i] = *(const bf16x8*)&A_lds[row * 32 + ((quad ^ (row & 3)) << 3)];
  }
#pragma unroll
  for (int j = 0; j < 2; ++j) {
    const int row = (w << 5) + j * 16 + ln15;
    bfr[j] = *(const bf16x8*)&B_lds[row * 32 + ((quad ^ (row & 3)) << 3)];
  }
#pragma unroll
  for (int i = 0; i < 4; ++i)
#pragma unroll
    for (int j = 0; j < 2; ++j)
      acc[i][j] = __builtin_amdgcn_mfma_f32_16x16x32_bf16(af[i], bfr[j], acc[i][j], 0, 0, 0);
}

__global__ __launch_bounds__(256) void out_gemm(
    const __bf16* __restrict__ A, const __bf16* __restrict__ Wo,
    const float* __restrict__ bo, float* __restrict__ out)
{
  __shared__ __align__(16) __bf16 lds[18432];   // 36 KB: 3 slots x 6144

  const int m0 = blockIdx.x * 64;
  const int n0 = blockIdx.y * 128;

  const int t = threadIdx.x, w = t >> 6, lane = t & 63;
  const int ln15 = lane & 15, quad = lane >> 4;

  f32x4 acc[4][2];
#pragma unroll
  for (int i = 0; i < 4; ++i)
#pragma unroll
    for (int j = 0; j < 2; ++j) acc[i][j] = (f32x4){0.f, 0.f, 0.f, 0.f};

  __bf16* s0 = lds;
  __bf16* s1 = lds + 6144;
  __bf16* s2 = lds + 12288;

  out_stage(A, Wo, m0, n0, 0,  s0, w, lane);
  out_stage(A, Wo, m0, n0, 32, s1, w, lane);

  int kt = 0;
#pragma unroll 1
  for (int i3 = 0; i3 < 10; ++i3) {
    VWAIT(3); __builtin_amdgcn_s_barrier();
    out_stage(A, Wo, m0, n0, kt + 64, s2, w, lane);
    out_step(s0, w, ln15, quad, acc);

    VWAIT(3); __builtin_amdgcn_s_barrier();
    out_stage(A, Wo, m0, n0, kt + 96, s0, w, lane);
    out_step(s1, w, ln15, quad, acc);

    VWAIT(3); __builtin_amdgcn_s_barrier();
    out_stage(A, Wo, m0, n0, kt + 128, s1, w, lane);
    out_step(s2, w, ln15, quad, acc);
    kt += 96;
  }
  VWAIT(3); __builtin_amdgcn_s_barrier();
  out_step(s0, w, ln15, quad, acc);
  VWAIT(0); __builtin_amdgcn_s_barrier();
  out_step(s1, w, ln15, quad, acc);

  float bj2[2];
#pragma unroll
  for (int j = 0; j < 2; ++j) bj2[j] = bo[n0 + (w << 5) + j * 16 + ln15];

  __syncthreads();                          // waves done reading tiles
  float* scrf = (float*)lds + (w << 9);     // per-wave 512-float scratch (2 KB)

  const int rdrow = lane & 15, rdseg = lane >> 4;
#pragma unroll
  for (int i = 0; i < 4; ++i) {
#pragma unroll
    for (int j = 0; j < 2; ++j) {
      f32x4 v;
#pragma unroll
      for (int rr = 0; rr < 4; ++rr) v[rr] = acc[i][j][rr] + bj2[j];
      *(f32x4*)&scrf[(j * 16 + ln15) * 16 + quad * 4] = v;   // col-major
    }
    const int m = m0 + i * 16 + rdrow;
    float* p = out + (size_t)m * DMODEL + n0 + (w << 5) + rdseg * 8;
#pragma unroll
    for (int cc = 0; cc < 2; ++cc) {
      f32x4 v;
#pragma unroll
      for (int e = 0; e < 4; ++e)
        v[e] = scrf[(rdseg * 8 + cc * 4 + e) * 16 + rdrow];
      *(f32x4*)&p[cc * 4] = v;
    }
  }
}

// ---------------------------------------------------------------------------
// softmax fragment build (T12): s holds S^T regs for one 32-key block
// (key = (r&3) + 8*(r>>2) + 4*hl, q = ln31). exp2 in place, then
// cvt_pk pairs + permlane32_swap reassemble the PV A-fragments entirely
// in registers — no P LDS round-trip.
// ---------------------------------------------------------------------------
__device__ __forceinline__ void softmax_frag(const f32x16& s, float& l,
                                             bf16x8& pfa, bf16x8& pfb)
{
  float p[16];
#pragma unroll
  for (int r = 0; r < 16; ++r) {
    p[r] = __builtin_amdgcn_exp2f(s[r]);
    l += p[r];
  }
  unsigned A0 = cvtpk_bf16(p[0],  p[1]);   // (0,1)   | (4,5)
  unsigned A1 = cvtpk_bf16(p[2],  p[3]);   // (2,3)   | (6,7)
  unsigned B0 = cvtpk_bf16(p[4],  p[5]);   // (8,9)   | (12,13)
  unsigned B1 = cvtpk_bf16(p[6],  p[7]);   // (10,11) | (14,15)
  unsigned C0 = cvtpk_bf16(p[8],  p[9]);   // (16,17) | (20,21)
  unsigned C1 = cvtpk_bf16(p[10], p[11]);  // (18,19) | (22,23)
  unsigned D0 = cvtpk_bf16(p[12], p[13]);  // (24,25) | (28,29)
  unsigned D1 = cvtpk_bf16(p[14], p[15]);  // (26,27) | (30,31)
  plswap(A0, B0);
  plswap(A1, B1);
  plswap(C0, D0);
  plswap(C1, D1);
  union { unsigned u[4]; bf16x8 v; } ua, ub;
  ua.u[0] = A0; ua.u[1] = A1; ua.u[2] = B0; ua.u[3] = B1;  // k 0..7 | 8..15
  ub.u[0] = C0; ub.u[1] = C1; ub.u[2] = D0; ub.u[3] = D1;  // k 16..23 | 24..31
  pfa = ua.v;
  pfb = ub.v;
}

// ---------------------------------------------------------------------------
// PV step: A-frag PF covers keys kh*64 + KS*16 + hl*8 .. +8
// ---------------------------------------------------------------------------
__device__ __forceinline__ void pvstep(const __bf16* Vs, int kh, int KS, int hl,
                                       int ln31, const bf16x8& PF,
                                       f32x16& o0, f32x16& o1)
{
  const int vchunk = (kh << 3) + 2 * KS + hl;
  bf16x8 vf0 = *(const bf16x8*)&Vs[ln31 * 128 + ((vchunk ^ (ln31 & 15)) << 3)];
  bf16x8 vf1 = *(const bf16x8*)&Vs[(32 + ln31) * 128 +
                                   ((vchunk ^ ((32 + ln31) & 15)) << 3)];
  o0 = __builtin_amdgcn_mfma_f32_32x32x16_bf16(PF, vf0, o0, 0, 0, 0);
  o1 = __builtin_amdgcn_mfma_f32_32x32x16_bf16(PF, vf1, o1, 0, 0, 0);
}

// per-128-key-tile compute for one wave (its 64-key half, two 32-key blocks)
// — R1-verified serial order.
__device__ __forceinline__ void attn_tile_compute(
    const __bf16* Ks, const __bf16* Vs, const bf16x8 (&qf)[4],
    int kh, int ln31, int hl, float& l_lane, f32x16& o0, f32x16& o1)
{
#pragma unroll
  for (int half = 0; half < 2; ++half) {
    f32x16 s;
#pragma unroll
    for (int r = 0; r < 16; ++r) s[r] = 0.f;
    const int kr = (kh << 6) + half * 32 + ln31;
    __builtin_amdgcn_s_setprio(1);
#pragma unroll
    for (int ks = 0; ks < 4; ++ks) {
      bf16x8 kf = *(const bf16x8*)&Ks[kr * 64 + (((2 * ks + hl) ^ (kr & 7)) << 3)];
      s = __builtin_amdgcn_mfma_f32_32x32x16_bf16(kf, qf[ks], s, 0, 0, 0);
    }
    __builtin_amdgcn_s_setprio(0);
    bf16x8 pa, pb;
    softmax_frag(s, l_lane, pa, pb);
    __builtin_amdgcn_s_setprio(1);
    pvstep(Vs, kh, half * 2 + 0, hl, ln31, pa, o0, o1);
    pvstep(Vs, kh, half * 2 + 1, hl, ln31, pb, o0, o1);
    __builtin_amdgcn_s_setprio(0);
  }
}

// ---------------------------------------------------------------------------
// Flash attention v14 — R1 compute path + T4 counted-vmcnt 2-SLOT K/V
// pipeline (mechanism validated by R8's GEMMs on this toolchain).
// Per tile j: VWAIT(4) [FIFO: tile-j's 4 gload_lds retired; tile-j+1's 4
// stay in flight] -> raw s_barrier [tile-j visible] -> compute(j, slot j%2)
// -> raw s_barrier [slot free] -> stage(j+2 -> slot j%2). Tile j+1's loads
// ride across BOTH barriers and land during compute(j) — the overlap R2's
// __syncthreads (implicit vmcnt(0)) destroyed. 2 barriers/tile (unchanged),
// zero full drains except the peeled last tile.
// LDS 80 KB: Q 16 | slot0 (K 16 + V 16) | slot1 (K 16 + V 16) -> 2 blocks/CU
// (same as before: grid 512 = 2/CU is binding). VGPR target 64: (512,4).
// ---------------------------------------------------------------------------
__global__ __launch_bounds__(512, 4) void attn_kernel(
    const __bf16* __restrict__ Qb, const __bf16* __restrict__ Kb,
    const __bf16* __restrict__ Vtb, __bf16* __restrict__ Ob)
{
  __shared__ __align__(16) __bf16 smem[5 * 128 * 64];   // 80 KB
  __bf16* QP = smem;            // Q tile [q128][dk64]
  __bf16* K0 = smem + 8192;     // slot0 K [key128][dk64]
  __bf16* V0 = smem + 16384;    // slot0 V [d64][key128]
  __bf16* K1 = smem + 24576;    // slot1 K
  __bf16* V1 = smem + 32768;    // slot1 V

  const int t = threadIdx.x, w = t >> 6, lane = t & 63;
  const int ln31 = lane & 31, hl = lane >> 5;
  const int g  = w & 3;         // q-group (32 rows of the 128-q tile)
  const int kh = w >> 2;        // key-half (64 keys) of the staged tile
  const int bh = blockIdx.x;    // b*NHEAD + h  (XCD-locality key)
  const int q0 = blockIdx.y * 128;
  const int bb = bh >> 4, hh = bh & 15;

  const __bf16* Qg = Qb + (size_t)bh * SEQ * DKH + (size_t)q0 * DKH;
  const __bf16* Kg = Kb + (size_t)bh * SEQ * DKH;
  const __bf16* Vg = Vtb + (size_t)bh * DKH * SEQ;

  // K/V tile stage: 4 gload_lds per thread per 128-key tile
  auto stage_kv = [&](int kt, __bf16* Ks, __bf16* Vs) {
#pragma unroll
    for (int issue = 0; issue < 2; ++issue) {
      const int cbase = issue * 512 + (w << 6);
      const int c = cbase + lane;
      const int krow = c >> 3;                        // K: 8 chunks/row
      const int kgoff = ((c & 7) ^ (krow & 7)) << 3;
      async16(Kg + (size_t)(kt + krow) * DKH + kgoff, Ks + cbase * 8);
      const int vrow = c >> 4;                        // V: 16 chunks/row
      const int vgoff = ((c & 15) ^ (vrow & 15)) << 3;
      async16(Vg + (size_t)vrow * SEQ + kt + vgoff, Vs + cbase * 8);
    }
  };

  // prologue: Q (2 loads/thread, oldest) then tiles 0,1 (4+4)
#pragma unroll
  for (int issue = 0; issue < 2; ++issue) {
    const int cbase = issue * 512 + (w << 6);
    const int c = cbase + lane;
    const int row = c >> 3;                         // 8 chunks per 64-elem row
    const int goff = ((c & 7) ^ (row & 7)) << 3;
    async16(Qg + (size_t)row * DKH + goff, QP + cbase * 8);
  }
  stage_kv(0, K0, V0);
  stage_kv(128, K1, V1);

  VWAIT(8);                          // FIFO: Q's 2 loads retired (8 tile loads out)
  __builtin_amdgcn_s_barrier();      // Q visible to all waves

  // Q B-fragments for this wave's 32 q-rows (held in regs for whole kernel)
  const int qrow = (g << 5) + ln31;
  bf16x8 qf[4];
#pragma unroll
  for (int ks = 0; ks < 4; ++ks) {
    const int chunk = ((2 * ks + hl) ^ (qrow & 7));
    qf[ks] = *(const bf16x8*)&QP[qrow * 64 + (chunk << 3)];
  }

  float l_lane = 0.f;          // partial row-sum for q-row `qrow` (this key-half)
  f32x16 o0, o1;               // partial O[32q][64d]: d-blocks 0/1; d = db*32+ln31
#pragma unroll
  for (int r = 0; r < 16; ++r) { o0[r] = 0.f; o1[r] = 0.f; }

  // main loop: tiles 0..13 (stages tiles 2..15); 2-unrolled, static slots
#pragma unroll 1
  for (int j = 0; j < 14; j += 2) {
    VWAIT(4); __builtin_amdgcn_s_barrier();          // tile j landed+visible
    attn_tile_compute(K0, V0, qf, kh, ln31, hl, l_lane, o0, o1);
    __builtin_amdgcn_s_barrier();                    // slot0 free
    stage_kv((j + 2) * 128, K0, V0);

    VWAIT(4); __builtin_amdgcn_s_barrier();          // tile j+1 landed+visible
    attn_tile_compute(K1, V1, qf, kh, ln31, hl, l_lane, o0, o1);
    __builtin_amdgcn_s_barrier();                    // slot1 free
    stage_kv((j + 3) * 128, K1, V1);
  }
  // peeled: tile 14 (slot0; tile 15's loads still in flight), then tile 15
  VWAIT(4); __builtin_amdgcn_s_barrier();
  attn_tile_compute(K0, V0, qf, kh, ln31, hl, l_lane, o0, o1);
  VWAIT(0); __builtin_amdgcn_s_barrier();
  attn_tile_compute(K1, V1, qf, kh, ln31, hl, l_lane, o0, o1);

  // ---- cross-wave combine: pair (w, w+4) holds same q-rows, disjoint keys.
  // Waves 4..7 dump partial O (8 KB each) + l into dead Q/K0/V0 LDS; waves
  // 0..3 sum, normalize, store.
  __syncthreads();                       // all K/V LDS reads done
  float* cmb = (float*)smem;             // pair region: [d64][q32] f32
  const int dsw = ln31 & 7;
  l_lane += __shfl_xor(l_lane, 32);      // both key-sub-blocks of this wave

  if (w >= 4) {
    float* base = cmb + (g << 11);
#pragma unroll
    for (int gg = 0; gg < 4; ++gg) {
      const int qq = ((2 * gg + hl) ^ dsw) << 2;   // swizzled q-quad slot
      f32x4 va, vb;
#pragma unroll
      for (int rr = 0; rr < 4; ++rr) { va[rr] = o0[4 * gg + rr]; vb[rr] = o1[4 * gg + rr]; }
      *(f32x4*)&base[ln31 * 32 + qq]        = va;   // d = ln31
      *(f32x4*)&base[(32 + ln31) * 32 + qq] = vb;   // d = 32+ln31
    }
    if (hl == 0) cmb[8192 + (g << 5) + ln31] = l_lane;   // l region
  }
  __syncthreads();
  if (w < 4) {
    float* base = cmb + (g << 11);
#pragma unroll
    for (int gg = 0; gg < 4; ++gg) {
      const int qq = ((2 * gg + hl) ^ dsw) << 2;
      const f32x4 va = *(const f32x4*)&base[ln31 * 32 + qq];
      const f32x4 vb = *(const f32x4*)&base[(32 + ln31) * 32 + qq];
#pragma unroll
      for (int rr = 0; rr < 4; ++rr) { o0[4 * gg + rr] += va[rr]; o1[4 * gg + rr] += vb[rr]; }
    }
    const float inv = 1.0f / (l_lane + cmb[8192 + (g << 5) + ln31]);

    // epilogue: O[b, q, h*64+d]; lane = d col; fetch inv via shfl
#pragma unroll
    for (int r = 0; r < 16; ++r) {
      const int qi = (r & 3) + 8 * (r >> 2) + 4 * hl;    // q within wave's 32
      const float iq = __shfl(inv, qi);                  // from lane qi (hl=0 half)
      const int q = q0 + (g << 5) + qi;
      __bf16* rowp = Ob + ((size_t)(bb * SEQ + q)) * DMODEL + hh * DKH;
      rowp[ln31]      = (__bf16)(o0[r] * iq);
      rowp[32 + ln31] = (__bf16)(o1[r] * iq);
    }
  }
}

// ---------------------------------------------------------------------------
extern "C" void kernel_launch(void* const* d_in, const int* in_sizes, int n_in,
                              void* d_out, int out_size, void* d_ws, size_t ws_size,
                              hipStream_t stream)
{
  const float* x  = (const float*)d_in[0];
  const float* Wq = (const float*)d_in[1];
  const float* bq = (const float*)d_in[2];
  const float* Wk = (const float*)d_in[3];
  const float* bk = (const float*)d_in[4];
  const float* Wv = (const float*)d_in[5];
  const float* bv = (const float*)d_in[6];
  const float* Wo = (const float*)d_in[7];
  const float* bo = (const float*)d_in[8];
  float*  out = (float*)d_out;
  __bf16* ws  = (__bf16*)d_ws;

  // fp32 -> bf16 for x and the 4 weight matrices (one launch)
  cvt_fp32_bf16<<<dim3(2048, 5, 1), 256, 0, stream>>>(x, Wq, Wk, Wv, Wo, ws);

  // Q,K,V projections (fused, grid.z picks the matrix)
  qkv_gemm<<<dim3(MTOT / 128, DMODEL / 128, 3), 256, 0, stream>>>(
      ws + XB, ws + WQB, bq, ws + WKB, bk, ws + WVB, bv, ws);

  // flash attention: (bh, q-tile of 128) = 512 blocks x 512 threads
  attn_kernel<<<dim3(BATCH * NHEAD, SEQ / 128), 512, 0, stream>>>(
      ws + QOFF, ws + KOFF, ws + VOFF, ws + OOFF);

  // output projection -> fp32 d_out (64x128 tiles, 512 blocks)
  out_gemm<<<dim3(MTOT / 64, DMODEL / 128), 256, 0, stream>>>(
      ws + OOFF, ws + WOB, bo, out);
}

// Round 10
// 174.810 us; speedup vs baseline: 1.0460x; 1.0460x over previous
//
#include <hip/hip_runtime.h>

// ---------- problem constants ----------
#define BATCH   2
#define SEQ     2048
#define DMODEL  1024
#define NHEAD   16
#define DKH     64
#define MTOT    (BATCH*SEQ)      // 4096 rows for the projection GEMMs
#define KDIM    DMODEL           // 1024 contraction for projections

// ws layout in bf16 elements (total 24M bf16 = 48 MB)
#define XB    0u                     // x bf16            [4096,1024]  4M
#define WQB   (4u*1024u*1024u)       // Wq bf16           [1024,1024]  1M
#define WKB   (5u*1024u*1024u)
#define WVB   (6u*1024u*1024u)
#define WOB   (7u*1024u*1024u)
#define QOFF  (8u*1024u*1024u)       // Q  [B,H,N,dk] (pre-scaled log2e/8) 4M
#define KOFF  (12u*1024u*1024u)      // K  [B,H,N,dk]                  4M
#define VOFF  (16u*1024u*1024u)      // V^T [B,H,dk,N]                 4M
#define OOFF  (20u*1024u*1024u)      // attn out, flat [B,N,D]         4M

typedef __bf16 bf16x8 __attribute__((ext_vector_type(8)));
typedef __bf16 bf16x4 __attribute__((ext_vector_type(4)));
typedef float  f32x4  __attribute__((ext_vector_type(4)));
typedef float  f32x16 __attribute__((ext_vector_type(16)));

// async global->LDS, 16B per lane; LDS dest is wave-uniform base (HW adds lane*16)
__device__ __forceinline__ void async16(const __bf16* g, __bf16* l) {
  __builtin_amdgcn_global_load_lds(
      (const __attribute__((address_space(1))) void*)g,
      (__attribute__((address_space(3))) void*)l, 16, 0, 0);
}

// counted waits (T4): compiler-level memory fence + hw wait, NO full drain.
// vmcnt is FIFO: waiting to <=N outstanding retires the oldest first.
#define VWAIT(N) asm volatile("s_waitcnt vmcnt(" #N ")" ::: "memory")

// packed f32x2 -> bf16x2 (dword): lo in low 16 bits (T12 recipe, no builtin)
__device__ __forceinline__ unsigned cvtpk_bf16(float lo, float hi) {
  unsigned r;
  asm("v_cvt_pk_bf16_f32 %0, %1, %2" : "=v"(r) : "v"(lo), "v"(hi));
  return r;
}
// v_permlane32_swap_b32: a.hi32lanes <-> b.lo32lanes
__device__ __forceinline__ void plswap(unsigned& a, unsigned& b) {
  asm("v_permlane32_swap_b32 %0, %1" : "+v"(a), "+v"(b));
}

// ---------------------------------------------------------------------------
// fp32 -> bf16 conversion: blockIdx.y selects tensor (0:x, 1..4:Wq/Wk/Wv/Wo)
// ---------------------------------------------------------------------------
__global__ __launch_bounds__(256) void cvt_fp32_bf16(
    const float* __restrict__ x,  const float* __restrict__ wq,
    const float* __restrict__ wk, const float* __restrict__ wv,
    const float* __restrict__ wo, __bf16* __restrict__ ws)
{
  const float* src; __bf16* dst; int n;
  switch (blockIdx.y) {
    case 0:  src = x;  dst = ws + XB;  n = 4 * 1024 * 1024; break;
    case 1:  src = wq; dst = ws + WQB; n = 1024 * 1024;     break;
    case 2:  src = wk; dst = ws + WKB; n = 1024 * 1024;     break;
    case 3:  src = wv; dst = ws + WVB; n = 1024 * 1024;     break;
    default: src = wo; dst = ws + WOB; n = 1024 * 1024;     break;
  }
  const int i = (blockIdx.x * 256 + threadIdx.x) * 8;
  if (i < n) {
    const float4 a = *(const float4*)(src + i);
    const float4 b = *(const float4*)(src + i + 4);
    bf16x8 o;
    o[0] = (__bf16)a.x; o[1] = (__bf16)a.y; o[2] = (__bf16)a.z; o[3] = (__bf16)a.w;
    o[4] = (__bf16)b.x; o[5] = (__bf16)b.y; o[6] = (__bf16)b.z; o[7] = (__bf16)b.w;
    *(bf16x8*)(dst + i) = o;
  }
}

// ---------------------------------------------------------------------------
// 128x128 NT-GEMM core, 8-WAVE (R10): wave w owns a 64x32 sub-tile
// (wr=(w>>2)*64, wc=(w&3)*32). 3-slot T4 K-loop (R8-verified): counted
// vmcnt + raw s_barrier, 1 barrier/K-step, prefetch 2 tiles ahead.
// Why 8 waves: 3 blocks/CU x 8 = 24 waves/CU (6/SIMD) vs 12 before —
// doubles the latency-hiding pool at UNCHANGED traffic/barriers (the R1
// attn lever applied to the GEMM). Staging: A 512 chunks + B 512 chunks
// per K-step over 512 threads = 1+1 per thread -> VWAIT(2) steady-state.
// LDS: 3 slots x (A 4096 | B 4096) = 48 KB (x3 blocks = 144 <= 160).
// ---------------------------------------------------------------------------
__device__ __forceinline__ void qkv_stage(
    const __bf16* __restrict__ A, const __bf16* __restrict__ W,
    int m0, int n0, int kt, __bf16* slot, int t)
{
  const int c    = t;                             // 0..511, one A + one B chunk
  const int row  = c >> 2;                        // 4 chunks (32 bf16) per row
  const int goff = ((c & 3) ^ (row & 3)) << 3;    // swizzled source chunk
  async16(A + (size_t)(m0 + row) * KDIM + kt + goff, slot + c * 8);
  async16(W + (size_t)(n0 + row) * KDIM + kt + goff, slot + 4096 + c * 8);
}

__device__ __forceinline__ void qkv_step(
    const __bf16* slot, int wr, int wc, int ln15, int quad, f32x4 (&acc)[4][2])
{
  const __bf16* A_lds = slot;
  const __bf16* B_lds = slot + 4096;
  bf16x8 af[4], bfr[2];
#pragma unroll
  for (int i = 0; i < 4; ++i) {
    const int row = wr + i * 16 + ln15;
    af[i] = *(const bf16x8*)&A_lds[row * 32 + ((quad ^ (row & 3)) << 3)];
  }
#pragma unroll
  for (int j = 0; j < 2; ++j) {
    const int row = wc + j * 16 + ln15;
    bfr[j] = *(const bf16x8*)&B_lds[row * 32 + ((quad ^ (row & 3)) << 3)];
  }
#pragma unroll
  for (int i = 0; i < 4; ++i)
#pragma unroll
    for (int j = 0; j < 2; ++j)
      acc[i][j] = __builtin_amdgcn_mfma_f32_16x16x32_bf16(af[i], bfr[j], acc[i][j], 0, 0, 0);
}

// ---------------------------------------------------------------------------
// Fused QKV projection, 8-wave: z=0 -> Q (scaled log2e/8) [B,H,N,dk];
// z=1 -> K; z=2 -> V transposed [B,H,dk,N]. Biases fp32.
// __launch_bounds__(512,3): 3 blocks/CU -> 6 waves/SIMD VGPR budget (~80);
// per-wave acc is only 32 f32 so it fits. Spill would show as FETCH blowup.
// ---------------------------------------------------------------------------
__global__ __launch_bounds__(512, 3) void qkv_gemm(
    const __bf16* __restrict__ X,
    const __bf16* __restrict__ Wq, const float* __restrict__ bq,
    const __bf16* __restrict__ Wk, const float* __restrict__ bk,
    const __bf16* __restrict__ Wv, const float* __restrict__ bv,
    __bf16* __restrict__ ws)
{
  __shared__ __align__(16) __bf16 lds[24576];   // 48 KB: 3 K-slots

  const int z = blockIdx.z;
  const __bf16* W    = (z == 0) ? Wq : (z == 1) ? Wk : Wv;
  const float*  bias = (z == 0) ? bq : (z == 1) ? bk : bv;
  __bf16* out = ws + ((z == 0) ? QOFF : (z == 1) ? KOFF : VOFF);
  // softmax runs in exp2 domain: fold 1/sqrt(dk) * log2(e) into Q
  const float scale = (z == 0) ? 0.125f * 1.44269504088896f : 1.0f;

  const int m0 = blockIdx.x * 128;
  const int n0 = blockIdx.y * 128;

  const int t = threadIdx.x, w = t >> 6, lane = t & 63;
  const int ln15 = lane & 15, quad = lane >> 4;
  const int wr = (w >> 2) << 6;   // wave row offset (0/64)
  const int wc = (w & 3) << 5;    // wave col offset (0/32/64/96)

  f32x4 acc[4][2];
#pragma unroll
  for (int i = 0; i < 4; ++i)
#pragma unroll
    for (int j = 0; j < 2; ++j) acc[i][j] = (f32x4){0.f, 0.f, 0.f, 0.f};

  __bf16* s0 = lds;
  __bf16* s1 = lds + 8192;
  __bf16* s2 = lds + 16384;

  // prologue: tiles 0,1 in flight (4 outstanding loads/thread)
  qkv_stage(X, W, m0, n0, 0,  s0, t);
  qkv_stage(X, W, m0, n0, 32, s1, t);

  // main loop: tiles 0..29, 3-unrolled for static slot rotation
  int kt = 0;
#pragma unroll 1
  for (int i3 = 0; i3 < 10; ++i3) {
    VWAIT(2); __builtin_amdgcn_s_barrier();
    qkv_stage(X, W, m0, n0, kt + 64, s2, t);
    qkv_step(s0, wr, wc, ln15, quad, acc);

    VWAIT(2); __builtin_amdgcn_s_barrier();
    qkv_stage(X, W, m0, n0, kt + 96, s0, t);
    qkv_step(s1, wr, wc, ln15, quad, acc);

    VWAIT(2); __builtin_amdgcn_s_barrier();
    qkv_stage(X, W, m0, n0, kt + 128, s1, t);
    qkv_step(s2, wr, wc, ln15, quad, acc);
    kt += 96;
  }
  // peeled tail: tile 30 (slot0, tile 31 still flying), then tile 31 (drain)
  VWAIT(2); __builtin_amdgcn_s_barrier();
  qkv_step(s0, wr, wc, ln15, quad, acc);
  VWAIT(0); __builtin_amdgcn_s_barrier();
  qkv_step(s1, wr, wc, ln15, quad, acc);

  // bias values for this wave's 32 columns (col = wc + j*16 + ln15)
  float bj2[2];
#pragma unroll
  for (int j = 0; j < 2; ++j) bj2[j] = bias[n0 + wc + j * 16 + ln15];

  __syncthreads();                     // all waves done reading K-tiles
  __bf16* scr = lds + (w << 10);       // per-wave 1024-elem scratch (2 KB)

  const int bb = m0 >> 11;             // batch (blocks never straddle)
  const int s_base = (m0 & 2047) + wr;
  const int h = (n0 + wc) >> 6;        // wc is 32-aligned: never straddles a head

  if (z != 2) {
    // ---- Q/K [B,H,N,dk]: row-major scratch [row16][col32], coalesced stores
    const int rdrow = lane & 15, rdseg = lane >> 4;   // rdseg 0..3 x 8 cols
#pragma unroll
    for (int i = 0; i < 4; ++i) {
#pragma unroll
      for (int j = 0; j < 2; ++j)
#pragma unroll
        for (int rr = 0; rr < 4; ++rr)
          scr[(quad * 4 + rr) * 32 + j * 16 + ln15] =
              (__bf16)((acc[i][j][rr] + bj2[j]) * scale);
      // wave-private scratch: compiler orders via lgkmcnt, no barrier
      bf16x8 v = *(const bf16x8*)&scr[rdrow * 32 + rdseg * 8];
      const int s = s_base + i * 16 + rdrow;
      __bf16* p = out + (((size_t)(bb * NHEAD + h)) * SEQ + s) * DKH
                      + (wc & 63) + rdseg * 8;
      *(bf16x8*)p = v;
    }
  } else {
    // ---- V^T [B,H,dk,N]: col-major scratch [d32][row16] does the transpose;
    // each lane then stores 16B contiguous in s.
#pragma unroll
    for (int i = 0; i < 4; ++i) {
#pragma unroll
      for (int j = 0; j < 2; ++j) {
        bf16x4 pk;
#pragma unroll
        for (int rr = 0; rr < 4; ++rr) pk[rr] = (__bf16)(acc[i][j][rr] + bj2[j]);
        *(bf16x4*)&scr[(j * 16 + ln15) * 16 + quad * 4] = pk;
      }
      const int dloc = lane >> 1, half = lane & 1;
      bf16x8 c0 = *(const bf16x8*)&scr[dloc * 16 + half * 8];
      __bf16* p = out + (((size_t)(bb * NHEAD + h)) * DKH + (wc & 63) + dloc) * SEQ
                      + s_base + i * 16 + half * 8;
      *(bf16x8*)p = c0;
    }
  }
}

// ---------------------------------------------------------------------------
// Output projection: d_out(fp32) = O[M,K]bf16 @ Wo[N,K]bf16^T + bo(fp32).
// 64x128 tile -> 512 blocks (2/CU). T4 triple-buffer K-loop (R8, verified).
// LDS: 3 x 6144 = 36 KB.  [CONTROL — unchanged from R8/R9]
// ---------------------------------------------------------------------------
__device__ __forceinline__ void out_stage(
    const __bf16* __restrict__ A, const __bf16* __restrict__ Wo,
    int m0, int n0, int kt, __bf16* slot, int w, int lane)
{
  {  // A: 64 rows x 4 chunks = 256 chunks = 1 issue
    const int c = (w << 6) + lane;
    const int row = c >> 2;
    const int goff = ((c & 3) ^ (row & 3)) << 3;
    async16(A + (size_t)(m0 + row) * KDIM + kt + goff, slot + c * 8);
  }
#pragma unroll
  for (int issue = 0; issue < 2; ++issue) {  // B: 128 rows x 4 chunks = 2 issues
    const int cbase = issue * 256 + (w << 6);
    const int c = cbase + lane;
    const int row = c >> 2;
    const int goff = ((c & 3) ^ (row & 3)) << 3;
    async16(Wo + (size_t)(n0 + row) * KDIM + kt + goff, slot + 2048 + cbase * 8);
  }
}

__device__ __forceinline__ void out_step(
    const __bf16* slot, int w, int ln15, int quad, f32x4 (&acc)[4][2])
{
  const __bf16* A_lds = slot;
  const __bf16* B_lds = slot + 2048;
  bf16x8 af[4], bfr[2];
#pragma unroll
  for (int i = 0; i < 4; ++i) {
    const int row = i * 16 + ln15;
    af[i] = *(const bf16x8*)&A_lds[row * 32 + ((quad ^ (row & 3)) << 3)];
  }
#pragma unroll
  for (int j = 0; j < 2; ++j) {
    const int row = (w << 5) + j * 16 + ln15;
    bfr[j] = *(const bf16x8*)&B_lds[row * 32 + ((quad ^ (row & 3)) << 3)];
  }
#pragma unroll
  for (int i = 0; i < 4; ++i)
#pragma unroll
    for (int j = 0; j < 2; ++j)
      acc[i][j] = __builtin_amdgcn_mfma_f32_16x16x32_bf16(af[i], bfr[j], acc[i][j], 0, 0, 0);
}

__global__ __launch_bounds__(256) void out_gemm(
    const __bf16* __restrict__ A, const __bf16* __restrict__ Wo,
    const float* __restrict__ bo, float* __restrict__ out)
{
  __shared__ __align__(16) __bf16 lds[18432];   // 36 KB: 3 slots x 6144

  const int m0 = blockIdx.x * 64;
  const int n0 = blockIdx.y * 128;

  const int t = threadIdx.x, w = t >> 6, lane = t & 63;
  const int ln15 = lane & 15, quad = lane >> 4;

  f32x4 acc[4][2];
#pragma unroll
  for (int i = 0; i < 4; ++i)
#pragma unroll
    for (int j = 0; j < 2; ++j) acc[i][j] = (f32x4){0.f, 0.f, 0.f, 0.f};

  __bf16* s0 = lds;
  __bf16* s1 = lds + 6144;
  __bf16* s2 = lds + 12288;

  out_stage(A, Wo, m0, n0, 0,  s0, w, lane);
  out_stage(A, Wo, m0, n0, 32, s1, w, lane);

  int kt = 0;
#pragma unroll 1
  for (int i3 = 0; i3 < 10; ++i3) {
    VWAIT(3); __builtin_amdgcn_s_barrier();
    out_stage(A, Wo, m0, n0, kt + 64, s2, w, lane);
    out_step(s0, w, ln15, quad, acc);

    VWAIT(3); __builtin_amdgcn_s_barrier();
    out_stage(A, Wo, m0, n0, kt + 96, s0, w, lane);
    out_step(s1, w, ln15, quad, acc);

    VWAIT(3); __builtin_amdgcn_s_barrier();
    out_stage(A, Wo, m0, n0, kt + 128, s1, w, lane);
    out_step(s2, w, ln15, quad, acc);
    kt += 96;
  }
  VWAIT(3); __builtin_amdgcn_s_barrier();
  out_step(s0, w, ln15, quad, acc);
  VWAIT(0); __builtin_amdgcn_s_barrier();
  out_step(s1, w, ln15, quad, acc);

  float bj2[2];
#pragma unroll
  for (int j = 0; j < 2; ++j) bj2[j] = bo[n0 + (w << 5) + j * 16 + ln15];

  __syncthreads();                          // waves done reading tiles
  float* scrf = (float*)lds + (w << 9);     // per-wave 512-float scratch (2 KB)

  const int rdrow = lane & 15, rdseg = lane >> 4;
#pragma unroll
  for (int i = 0; i < 4; ++i) {
#pragma unroll
    for (int j = 0; j < 2; ++j) {
      f32x4 v;
#pragma unroll
      for (int rr = 0; rr < 4; ++rr) v[rr] = acc[i][j][rr] + bj2[j];
      *(f32x4*)&scrf[(j * 16 + ln15) * 16 + quad * 4] = v;   // col-major
    }
    const int m = m0 + i * 16 + rdrow;
    float* p = out + (size_t)m * DMODEL + n0 + (w << 5) + rdseg * 8;
#pragma unroll
    for (int cc = 0; cc < 2; ++cc) {
      f32x4 v;
#pragma unroll
      for (int e = 0; e < 4; ++e)
        v[e] = scrf[(rdseg * 8 + cc * 4 + e) * 16 + rdrow];
      *(f32x4*)&p[cc * 4] = v;
    }
  }
}

// ---------------------------------------------------------------------------
// softmax fragment build (T12): s holds S^T regs for one 32-key block
// (key = (r&3) + 8*(r>>2) + 4*hl, q = ln31). exp2 in place, then
// cvt_pk pairs + permlane32_swap reassemble the PV A-fragments entirely
// in registers — no P LDS round-trip.
// ---------------------------------------------------------------------------
__device__ __forceinline__ void softmax_frag(const f32x16& s, float& l,
                                             bf16x8& pfa, bf16x8& pfb)
{
  float p[16];
#pragma unroll
  for (int r = 0; r < 16; ++r) {
    p[r] = __builtin_amdgcn_exp2f(s[r]);
    l += p[r];
  }
  unsigned A0 = cvtpk_bf16(p[0],  p[1]);   // (0,1)   | (4,5)
  unsigned A1 = cvtpk_bf16(p[2],  p[3]);   // (2,3)   | (6,7)
  unsigned B0 = cvtpk_bf16(p[4],  p[5]);   // (8,9)   | (12,13)
  unsigned B1 = cvtpk_bf16(p[6],  p[7]);   // (10,11) | (14,15)
  unsigned C0 = cvtpk_bf16(p[8],  p[9]);   // (16,17) | (20,21)
  unsigned C1 = cvtpk_bf16(p[10], p[11]);  // (18,19) | (22,23)
  unsigned D0 = cvtpk_bf16(p[12], p[13]);  // (24,25) | (28,29)
  unsigned D1 = cvtpk_bf16(p[14], p[15]);  // (26,27) | (30,31)
  plswap(A0, B0);
  plswap(A1, B1);
  plswap(C0, D0);
  plswap(C1, D1);
  union { unsigned u[4]; bf16x8 v; } ua, ub;
  ua.u[0] = A0; ua.u[1] = A1; ua.u[2] = B0; ua.u[3] = B1;  // k 0..7 | 8..15
  ub.u[0] = C0; ub.u[1] = C1; ub.u[2] = D0; ub.u[3] = D1;  // k 16..23 | 24..31
  pfa = ua.v;
  pfb = ub.v;
}

// ---------------------------------------------------------------------------
// PV step: A-frag PF covers keys kh*64 + KS*16 + hl*8 .. +8
// ---------------------------------------------------------------------------
__device__ __forceinline__ void pvstep(const __bf16* Vs, int kh, int KS, int hl,
                                       int ln31, const bf16x8& PF,
                                       f32x16& o0, f32x16& o1)
{
  const int vchunk = (kh << 3) + 2 * KS + hl;
  bf16x8 vf0 = *(const bf16x8*)&Vs[ln31 * 128 + ((vchunk ^ (ln31 & 15)) << 3)];
  bf16x8 vf1 = *(const bf16x8*)&Vs[(32 + ln31) * 128 +
                                   ((vchunk ^ ((32 + ln31) & 15)) << 3)];
  o0 = __builtin_amdgcn_mfma_f32_32x32x16_bf16(PF, vf0, o0, 0, 0, 0);
  o1 = __builtin_amdgcn_mfma_f32_32x32x16_bf16(PF, vf1, o1, 0, 0, 0);
}

// per-128-key-tile compute for one wave (its 64-key half, two 32-key blocks)
// — R1-verified serial order.
__device__ __forceinline__ void attn_tile_compute(
    const __bf16* Ks, const __bf16* Vs, const bf16x8 (&qf)[4],
    int kh, int ln31, int hl, float& l_lane, f32x16& o0, f32x16& o1)
{
#pragma unroll
  for (int half = 0; half < 2; ++half) {
    f32x16 s;
#pragma unroll
    for (int r = 0; r < 16; ++r) s[r] = 0.f;
    const int kr = (kh << 6) + half * 32 + ln31;
    __builtin_amdgcn_s_setprio(1);
#pragma unroll
    for (int ks = 0; ks < 4; ++ks) {
      bf16x8 kf = *(const bf16x8*)&Ks[kr * 64 + (((2 * ks + hl) ^ (kr & 7)) << 3)];
      s = __builtin_amdgcn_mfma_f32_32x32x16_bf16(kf, qf[ks], s, 0, 0, 0);
    }
    __builtin_amdgcn_s_setprio(0);
    bf16x8 pa, pb;
    softmax_frag(s, l_lane, pa, pb);
    __builtin_amdgcn_s_setprio(1);
    pvstep(Vs, kh, half * 2 + 0, hl, ln31, pa, o0, o1);
    pvstep(Vs, kh, half * 2 + 1, hl, ln31, pb, o0, o1);
    __builtin_amdgcn_s_setprio(0);
  }
}

// ---------------------------------------------------------------------------
// Flash attention — R9 version unchanged (43.2-43.7 µs; converged after 7
// structural attempts). T4 counted-vmcnt 2-slot K/V pipeline. [CONTROL]
// ---------------------------------------------------------------------------
__global__ __launch_bounds__(512, 4) void attn_kernel(
    const __bf16* __restrict__ Qb, const __bf16* __restrict__ Kb,
    const __bf16* __restrict__ Vtb, __bf16* __restrict__ Ob)
{
  __shared__ __align__(16) __bf16 smem[5 * 128 * 64];   // 80 KB
  __bf16* QP = smem;            // Q tile [q128][dk64]
  __bf16* K0 = smem + 8192;     // slot0 K [key128][dk64]
  __bf16* V0 = smem + 16384;    // slot0 V [d64][key128]
  __bf16* K1 = smem + 24576;    // slot1 K
  __bf16* V1 = smem + 32768;    // slot1 V

  const int t = threadIdx.x, w = t >> 6, lane = t & 63;
  const int ln31 = lane & 31, hl = lane >> 5;
  const int g  = w & 3;         // q-group (32 rows of the 128-q tile)
  const int kh = w >> 2;        // key-half (64 keys) of the staged tile
  const int bh = blockIdx.x;    // b*NHEAD + h  (XCD-locality key)
  const int q0 = blockIdx.y * 128;
  const int bb = bh >> 4, hh = bh & 15;

  const __bf16* Qg = Qb + (size_t)bh * SEQ * DKH + (size_t)q0 * DKH;
  const __bf16* Kg = Kb + (size_t)bh * SEQ * DKH;
  const __bf16* Vg = Vtb + (size_t)bh * DKH * SEQ;

  // K/V tile stage: 4 gload_lds per thread per 128-key tile
  auto stage_kv = [&](int kt, __bf16* Ks, __bf16* Vs) {
#pragma unroll
    for (int issue = 0; issue < 2; ++issue) {
      const int cbase = issue * 512 + (w << 6);
      const int c = cbase + lane;
      const int krow = c >> 3;                        // K: 8 chunks/row
      const int kgoff = ((c & 7) ^ (krow & 7)) << 3;
      async16(Kg + (size_t)(kt + krow) * DKH + kgoff, Ks + cbase * 8);
      const int vrow = c >> 4;                        // V: 16 chunks/row
      const int vgoff = ((c & 15) ^ (vrow & 15)) << 3;
      async16(Vg + (size_t)vrow * SEQ + kt + vgoff, Vs + cbase * 8);
    }
  };

  // prologue: Q (2 loads/thread, oldest) then tiles 0,1 (4+4)
#pragma unroll
  for (int issue = 0; issue < 2; ++issue) {
    const int cbase = issue * 512 + (w << 6);
    const int c = cbase + lane;
    const int row = c >> 3;                         // 8 chunks per 64-elem row
    const int goff = ((c & 7) ^ (row & 7)) << 3;
    async16(Qg + (size_t)row * DKH + goff, QP + cbase * 8);
  }
  stage_kv(0, K0, V0);
  stage_kv(128, K1, V1);

  VWAIT(8);                          // FIFO: Q's 2 loads retired (8 tile loads out)
  __builtin_amdgcn_s_barrier();      // Q visible to all waves

  // Q B-fragments for this wave's 32 q-rows (held in regs for whole kernel)
  const int qrow = (g << 5) + ln31;
  bf16x8 qf[4];
#pragma unroll
  for (int ks = 0; ks < 4; ++ks) {
    const int chunk = ((2 * ks + hl) ^ (qrow & 7));
    qf[ks] = *(const bf16x8*)&QP[qrow * 64 + (chunk << 3)];
  }

  float l_lane = 0.f;          // partial row-sum for q-row `qrow` (this key-half)
  f32x16 o0, o1;               // partial O[32q][64d]: d-blocks 0/1; d = db*32+ln31
#pragma unroll
  for (int r = 0; r < 16; ++r) { o0[r] = 0.f; o1[r] = 0.f; }

  // main loop: tiles 0..13 (stages tiles 2..15); 2-unrolled, static slots
#pragma unroll 1
  for (int j = 0; j < 14; j += 2) {
    VWAIT(4); __builtin_amdgcn_s_barrier();          // tile j landed+visible
    attn_tile_compute(K0, V0, qf, kh, ln31, hl, l_lane, o0, o1);
    __builtin_amdgcn_s_barrier();                    // slot0 free
    stage_kv((j + 2) * 128, K0, V0);

    VWAIT(4); __builtin_amdgcn_s_barrier();          // tile j+1 landed+visible
    attn_tile_compute(K1, V1, qf, kh, ln31, hl, l_lane, o0, o1);
    __builtin_amdgcn_s_barrier();                    // slot1 free
    stage_kv((j + 3) * 128, K1, V1);
  }
  // peeled: tile 14 (slot0; tile 15's loads still in flight), then tile 15
  VWAIT(4); __builtin_amdgcn_s_barrier();
  attn_tile_compute(K0, V0, qf, kh, ln31, hl, l_lane, o0, o1);
  VWAIT(0); __builtin_amdgcn_s_barrier();
  attn_tile_compute(K1, V1, qf, kh, ln31, hl, l_lane, o0, o1);

  // ---- cross-wave combine: pair (w, w+4) holds same q-rows, disjoint keys.
  // Waves 4..7 dump partial O (8 KB each) + l into dead Q/K0/V0 LDS; waves
  // 0..3 sum, normalize, store.
  __syncthreads();                       // all K/V LDS reads done
  float* cmb = (float*)smem;             // pair region: [d64][q32] f32
  const int dsw = ln31 & 7;
  l_lane += __shfl_xor(l_lane, 32);      // both key-sub-blocks of this wave

  if (w >= 4) {
    float* base = cmb + (g << 11);
#pragma unroll
    for (int gg = 0; gg < 4; ++gg) {
      const int qq = ((2 * gg + hl) ^ dsw) << 2;   // swizzled q-quad slot
      f32x4 va, vb;
#pragma unroll
      for (int rr = 0; rr < 4; ++rr) { va[rr] = o0[4 * gg + rr]; vb[rr] = o1[4 * gg + rr]; }
      *(f32x4*)&base[ln31 * 32 + qq]        = va;   // d = ln31
      *(f32x4*)&base[(32 + ln31) * 32 + qq] = vb;   // d = 32+ln31
    }
    if (hl == 0) cmb[8192 + (g << 5) + ln31] = l_lane;   // l region
  }
  __syncthreads();
  if (w < 4) {
    float* base = cmb + (g << 11);
#pragma unroll
    for (int gg = 0; gg < 4; ++gg) {
      const int qq = ((2 * gg + hl) ^ dsw) << 2;
      const f32x4 va = *(const f32x4*)&base[ln31 * 32 + qq];
      const f32x4 vb = *(const f32x4*)&base[(32 + ln31) * 32 + qq];
#pragma unroll
      for (int rr = 0; rr < 4; ++rr) { o0[4 * gg + rr] += va[rr]; o1[4 * gg + rr] += vb[rr]; }
    }
    const float inv = 1.0f / (l_lane + cmb[8192 + (g << 5) + ln31]);

    // epilogue: O[b, q, h*64+d]; lane = d col; fetch inv via shfl
#pragma unroll
    for (int r = 0; r < 16; ++r) {
      const int qi = (r & 3) + 8 * (r >> 2) + 4 * hl;    // q within wave's 32
      const float iq = __shfl(inv, qi);                  // from lane qi (hl=0 half)
      const int q = q0 + (g << 5) + qi;
      __bf16* rowp = Ob + ((size_t)(bb * SEQ + q)) * DMODEL + hh * DKH;
      rowp[ln31]      = (__bf16)(o0[r] * iq);
      rowp[32 + ln31] = (__bf16)(o1[r] * iq);
    }
  }
}

// ---------------------------------------------------------------------------
extern "C" void kernel_launch(void* const* d_in, const int* in_sizes, int n_in,
                              void* d_out, int out_size, void* d_ws, size_t ws_size,
                              hipStream_t stream)
{
  const float* x  = (const float*)d_in[0];
  const float* Wq = (const float*)d_in[1];
  const float* bq = (const float*)d_in[2];
  const float* Wk = (const float*)d_in[3];
  const float* bk = (const float*)d_in[4];
  const float* Wv = (const float*)d_in[5];
  const float* bv = (const float*)d_in[6];
  const float* Wo = (const float*)d_in[7];
  const float* bo = (const float*)d_in[8];
  float*  out = (float*)d_out;
  __bf16* ws  = (__bf16*)d_ws;

  // fp32 -> bf16 for x and the 4 weight matrices (one launch)
  cvt_fp32_bf16<<<dim3(2048, 5, 1), 256, 0, stream>>>(x, Wq, Wk, Wv, Wo, ws);

  // Q,K,V projections (fused, grid.z picks the matrix) — 8-wave blocks
  qkv_gemm<<<dim3(MTOT / 128, DMODEL / 128, 3), 512, 0, stream>>>(
      ws + XB, ws + WQB, bq, ws + WKB, bk, ws + WVB, bv, ws);

  // flash attention: (bh, q-tile of 128) = 512 blocks x 512 threads
  attn_kernel<<<dim3(BATCH * NHEAD, SEQ / 128), 512, 0, stream>>>(
      ws + QOFF, ws + KOFF, ws + VOFF, ws + OOFF);

  // output projection -> fp32 d_out (64x128 tiles, 512 blocks)
  out_gemm<<<dim3(MTOT / 64, DMODEL / 128), 256, 0, stream>>>(
      ws + OOFF, ws + WOB, bo, out);
}